// Round 13
// baseline (223.495 us; speedup 1.0000x reference)
//
#include <hip/hip_runtime.h>

#define S_LEN 8192
#define C_CTX 21
#define E_DIM 128
#define G_DIM 36
#define H_DIM 1024
#define T_TAG 32
#define D_RAW 3444          // 21*(128+36)
#define DP 3456             // emb-first K layout: 21*128=2688 emb | 756 gz | 12 pad
#define GZP 768             // padded gz width
#define START_TAG 30
#define STOP_TAG 31
#define NEGV -10000.0f
#define K_CHUNKS 64
#define L_CHUNK 128         // K_CHUNKS * L_CHUNK == S_LEN

typedef __bf16 bf16_t;
typedef __bf16 bf16x4 __attribute__((ext_vector_type(4)));
typedef __bf16 bf16x8 __attribute__((ext_vector_type(8)));
typedef float  f32x4  __attribute__((ext_vector_type(4)));

__device__ inline void async_copy16(const bf16_t* g, bf16_t* l) {
    __builtin_amdgcn_global_load_lds(
        (const __attribute__((address_space(1))) void*)g,
        (__attribute__((address_space(3))) void*)l, 16, 0, 0);
}

// ---------------- Phase 0: materialize W1b (emb-first K order), Xg, emb_bf --
// blocks 0..1023: W1b rows | 1024..3071: Xg (4 seq rows each) | 3072..3571: emb->bf16
__global__ void build_all(const int* __restrict__ ctx, const float* __restrict__ gz,
                          const float* __restrict__ emb, const float* __restrict__ w1,
                          bf16_t* __restrict__ Xg, bf16_t* __restrict__ W,
                          bf16_t* __restrict__ EB) {
    const int b = blockIdx.x;
    if (b < 1024) {                       // W1b row h, permuted K
        const int h = b;
        for (int g = threadIdx.x; g < DP / 4; g += 256) {
            bf16x4 o;
            if (g < 672) {                // emb region: knew = g*4; c=knew>>7, e=knew&127
                const int knew = g * 4;
                const float4 v = *(const float4*)&w1[(size_t)h * D_RAW + (knew >> 7) * 164 + (knew & 127)];
                o = bf16x4{(bf16_t)v.x, (bf16_t)v.y, (bf16_t)v.z, (bf16_t)v.w};
            } else {                      // gz region: m = g*4-2688 -> c=m/36, j=m%36
                const int m = g * 4 - 2688;
                float t[4];
#pragma unroll
                for (int u = 0; u < 4; ++u) {
                    const int mm = m + u;
                    t[u] = (mm < 756) ? w1[(size_t)h * D_RAW + (mm / 36) * 164 + 128 + (mm % 36)] : 0.f;
                }
                o = bf16x4{(bf16_t)t[0], (bf16_t)t[1], (bf16_t)t[2], (bf16_t)t[3]};
            }
            *(bf16x4*)&W[(size_t)h * DP + g * 4] = o;
        }
    } else if (b < 3072) {                // Xg: packed gz copy + pad (756 -> 768)
        const int s_base = (b - 1024) * 4;
        for (int g = threadIdx.x; g < 4 * 192; g += 256) {
            const int r = g / 192, gg = g - r * 192;
            const int s = s_base + r;
            bf16x4 o = bf16x4{(bf16_t)0.f, (bf16_t)0.f, (bf16_t)0.f, (bf16_t)0.f};
            if (gg < 189) {               // 189*4 = 756 exactly
                const float4 v = *(const float4*)&gz[(size_t)s * 756 + gg * 4];
                o = bf16x4{(bf16_t)v.x, (bf16_t)v.y, (bf16_t)v.z, (bf16_t)v.w};
            }
            *(bf16x4*)&Xg[(size_t)s * GZP + gg * 4] = o;
        }
    } else {                              // emb f32 -> bf16, flat 8000*128
        const size_t base = (size_t)(b - 3072) * 2048;
        for (int g = threadIdx.x; g < 512; g += 256) {
            const float4 v = *(const float4*)&emb[base + g * 4];
            bf16x4 o = bf16x4{(bf16_t)v.x, (bf16_t)v.y, (bf16_t)v.z, (bf16_t)v.w};
            *(bf16x4*)&EB[base + g * 4] = o;
        }
    }
}

// ---------------- Phase 1: h = relu(X @ W1^T + b1); Fp = h @ w2_slice^T ----
// 128x128 tile, BK=64, 512 threads (8 waves, 2M x 4N, 64x32 per wave),
// 2 blocks/CU => 16 waves/CU = 4 waves/SIMD (was 2 at 4-wave blocks).
// Round-12's PMC: matrix 45% / LDS 28% / VALU 27% — no pipe saturated, so
// gemm1 was dependency-bound at 2 waves/SIMD; doubling waves/SIMD gives the
// scheduler twice the issue sources to cover ds_read latency + barrier skew.
// Same double-buffer, prefetch distance 1, one barrier per tile, round-9
// loop order (frag ds_reads -> stage issues -> MFMA -> vmcnt(0) -> barrier).
// Verified kg^(row&7) swizzle; emb A-tiles gather from EB via ctx LDS cache;
// fused feats epilogue (wave -> 16 rows x 32 tags).
__global__ __launch_bounds__(512) void gemm1(const int* __restrict__ ctx,
                                             const bf16_t* __restrict__ EB,
                                             const bf16_t* __restrict__ Xg,
                                             const bf16_t* __restrict__ W,
                                             const float* __restrict__ b1,
                                             const float* __restrict__ w2,
                                             const float* __restrict__ b2,
                                             float* __restrict__ Fp) {
    __shared__ bf16_t As[2][128 * 64];        // 2 x 16 KB
    __shared__ bf16_t Bs[2][128 * 64];        // 2 x 16 KB
    __shared__ unsigned short ctxs[128 * 21]; // 5.375 KB (total 69.4 KB -> 2 blocks/CU)
    const int tid  = threadIdx.x;
    const int wave = tid >> 6, lane = tid & 63;
    const int s0 = blockIdx.x * 128, h0 = blockIdx.y * 128;
    const int wm = (wave >> 2) * 64;     // 2 wave-rows (0, 64)
    const int wn = (wave & 3) * 32;      // 4 wave-cols (0, 32, 64, 96)

    const int arow = tid >> 3;                         // 0..63
    const int akg  = (tid & 7) ^ (arow & 7);           // inverse-swizzled source k-group
    const bf16_t* gB = W + (size_t)(h0 + arow) * DP + akg * 8;

    const int lrow  = lane & 15;
    const int khalf = lane >> 4;         // 0..3
    const int lr7   = lrow & 7;

    // ctx table -> LDS (u16): rows s0..s0+127, flat copy
    for (int j = tid; j < 128 * C_CTX; j += 512)
        ctxs[j] = (unsigned short)ctx[s0 * C_CTX + j];
    asm volatile("s_waitcnt lgkmcnt(0)" ::: "memory");
    __builtin_amdgcn_s_barrier();

    // prologue: stage tile 0 (emb, c=0) into buf 0 — 4 loads/thread
    {
        const int e0 = akg * 8;
#pragma unroll
        for (int i = 0; i < 2; ++i) {
            const int cv = ctxs[(i * 64 + arow) * 21];
            async_copy16(EB + (size_t)cv * 128 + e0, &As[0][(i * 512 + tid) * 8]);
        }
#pragma unroll
        for (int i = 0; i < 2; ++i)
            async_copy16(gB + (size_t)i * 64 * DP, &Bs[0][(i * 512 + tid) * 8]);
    }
    asm volatile("s_waitcnt vmcnt(0)" ::: "memory");
    __builtin_amdgcn_s_barrier();

    f32x4 acc[4][2] = {};
    const int NT = DP / 64;              // 54 (tiles 0..41 emb, 42..53 gz)
    for (int t = 0; t < NT; ++t) {
        const int cur = t & 1, nxt = cur ^ 1;
        const int tt = t + 1;
        const bool st = tt < NT;

        // register fragments for this K-tile: 8 A + 4 B = 12 ds_read_b128
        bf16x8 a[2][4];        // [ks][mt]
        bf16x8 b[2][2];        // [ks][nt]
#pragma unroll
        for (int ks = 0; ks < 2; ++ks) {
            const int kgr = ((ks * 4 + khalf) ^ lr7) * 8;
#pragma unroll
            for (int mt = 0; mt < 4; ++mt)
                a[ks][mt] = *(const bf16x8*)&As[cur][(wm + mt * 16 + lrow) * 64 + kgr];
#pragma unroll
            for (int nt = 0; nt < 2; ++nt)
                b[ks][nt] = *(const bf16x8*)&Bs[cur][(wn + nt * 16 + lrow) * 64 + kgr];
        }
        // stage next tile into the other buffer (its readers finished at t-1)
        if (st) {
            if (tt < 42) {
                const int c_ = tt >> 1;
                const int e0 = (tt & 1) * 64 + akg * 8;
#pragma unroll
                for (int i = 0; i < 2; ++i) {
                    const int cv = ctxs[(i * 64 + arow) * 21 + c_];
                    async_copy16(EB + (size_t)cv * 128 + e0, &As[nxt][(i * 512 + tid) * 8]);
                }
            } else {
                const int m0 = (tt - 42) * 64 + akg * 8;
#pragma unroll
                for (int i = 0; i < 2; ++i)
                    async_copy16(Xg + (size_t)(s0 + i * 64 + arow) * GZP + m0, &As[nxt][(i * 512 + tid) * 8]);
            }
#pragma unroll
            for (int i = 0; i < 2; ++i)
                async_copy16(gB + (size_t)i * 64 * DP + tt * 64, &Bs[nxt][(i * 512 + tid) * 8]);
        }
        __builtin_amdgcn_s_setprio(1);
#pragma unroll
        for (int ks = 0; ks < 2; ++ks)
#pragma unroll
            for (int mt = 0; mt < 4; ++mt)
#pragma unroll
                for (int nt = 0; nt < 2; ++nt)
                    acc[mt][nt] = __builtin_amdgcn_mfma_f32_16x16x32_bf16(
                        a[ks][mt], b[ks][nt], acc[mt][nt], 0, 0, 0);
        __builtin_amdgcn_s_setprio(0);
        if (st) asm volatile("s_waitcnt vmcnt(0)" ::: "memory");
        __builtin_amdgcn_s_barrier();
    }

    // ---- fused feats epilogue ----
    bf16_t* Hl = &As[0][0];              // 128 x 128 bf16 (32 KB, spans As[0..1])
    bf16_t* Wl = &Bs[0][0];              // 32 x 128 bf16 (8 KB)

    // stage w2 slice: 32 tags x 128 h (f32 -> bf16), 8 values/thread
    {
        const int t8 = tid >> 4;            // 0..31 tag
        const int hl = tid & 15;            // 0..15 k-group
        const float* wsrc = w2 + (size_t)t8 * H_DIM + h0 + hl * 8;
        const float4 y0 = *(const float4*)wsrc;
        const float4 y1 = *(const float4*)(wsrc + 4);
        bf16x8 wv = {(bf16_t)y0.x, (bf16_t)y0.y, (bf16_t)y0.z, (bf16_t)y0.w,
                     (bf16_t)y1.x, (bf16_t)y1.y, (bf16_t)y1.z, (bf16_t)y1.w};
        *(bf16x8*)&Wl[(t8 * 16 + (hl ^ (t8 & 7))) * 8] = wv;
    }

    // H tile (relu + bf16) -> LDS, swizzled: Hl[s][ (j/8 ^ s&7)*8 + j%8 ]
    const int crow = (lane >> 4) * 4;
    const int ccol = lane & 15;
#pragma unroll
    for (int nt = 0; nt < 2; ++nt) {
        const int jl = wn + nt * 16 + ccol;          // 0..127 local h
        const float bv = b1[h0 + jl];
#pragma unroll
        for (int mt = 0; mt < 4; ++mt) {
#pragma unroll
            for (int r = 0; r < 4; ++r) {
                const int sl = wm + mt * 16 + crow + r;    // 0..127 local s
                const float v = acc[mt][nt][r] + bv;
                Hl[sl * 128 + ((jl >> 3) ^ (sl & 7)) * 8 + (jl & 7)] = (bf16_t)fmaxf(v, 0.f);
            }
        }
    }
    __syncthreads();

    // mini-GEMM: Fpart[s][t] = H[s][:] . w2[t][:] over this 128-h slice.
    // wave handles 16 s-rows x all 32 tags; K=128 in 4 ks-steps of 32.
    f32x4 acc2[2] = {};
    const int wm2 = wave * 16;
#pragma unroll
    for (int ks = 0; ks < 4; ++ks) {
        const int slot = ((ks * 4 + khalf) ^ lr7) * 8;
        bf16x8 ah = *(const bf16x8*)&Hl[(wm2 + lrow) * 128 + slot];
        bf16x8 bw[2];
#pragma unroll
        for (int nt = 0; nt < 2; ++nt)
            bw[nt] = *(const bf16x8*)&Wl[(nt * 16 + lrow) * 128 + slot];
#pragma unroll
        for (int nt = 0; nt < 2; ++nt)
            acc2[nt] = __builtin_amdgcn_mfma_f32_16x16x32_bf16(ah, bw[nt], acc2[nt], 0, 0, 0);
    }
    const int bj = h0 >> 7;
#pragma unroll
    for (int nt = 0; nt < 2; ++nt) {
        const int tcol = nt * 16 + ccol;
        const float badd = (bj == 7) ? b2[tcol] : 0.f;
#pragma unroll
        for (int r = 0; r < 4; ++r) {
            const int sr = s0 + wm2 + crow + r;
            Fp[((size_t)bj * S_LEN + sr) * T_TAG + tcol] = acc2[nt][r] + badd;
        }
    }
}

// ---------------- CRF pass A: per-chunk matrix-chain products + gold partial
// ONE chain per 64-lane wave; 2048 waves = 2 waves/SIMD. fl (the chunk's F
// rows, already in LDS for the chain) additionally feeds a per-chunk gold
// partial computed by the (blockIdx&3)==0 duplicate. Replaces the final
// fold's strided gold pass and the Fsum buffer entirely.
__global__ __launch_bounds__(512) void crfA(const float* __restrict__ Fp,
                                            const float* __restrict__ trans,
                                            float* __restrict__ QT,
                                            float* __restrict__ sigma,
                                            const int* __restrict__ lab,
                                            float* __restrict__ gold_part) {
    __shared__ float fl[L_CHUNK * 32];
    __shared__ float vb[8][64];
    __shared__ float wred[8];
    const int c    = blockIdx.x >> 2;
    const int tid  = threadIdx.x;
    const int wave = tid >> 6;
    const int lane = tid & 63;
    const int n    = lane & 31;
    const int h    = lane >> 5;                 // half: k in [h*16, h*16+16)
    const int p    = ((blockIdx.x & 3) << 3) + wave;
    const int s0   = c * L_CHUNK;
    for (int i = tid; i < L_CHUNK * 32; i += 512) {
        const size_t idx = (size_t)s0 * 32 + i;
        float accf = 0.f;
#pragma unroll
        for (int j = 0; j < 8; ++j) accf += Fp[(size_t)j * S_LEN * T_TAG + idx];
        fl[i] = accf;
    }
    __syncthreads();

    // gold partial (one duplicate block per chunk)
    const bool goldblk = (blockIdx.x & 3) == 0;
    float gterm = 0.f;
    if (goldblk && tid < L_CHUNK) {
        const int s  = s0 + tid;
        const int tg = lab[s];
        const int tp = (s == 0) ? START_TAG : lab[s - 1];
        gterm = fl[tid * 32 + tg] + trans[tg * T_TAG + tp];
    }
#pragma unroll
    for (int off = 32; off; off >>= 1) gterm += __shfl_down(gterm, off, 64);
    if (goldblk && lane == 0) wred[wave] = gterm;
    __syncthreads();
    if (goldblk && tid == 0) {
        float gsum = 0.f;
#pragma unroll
        for (int i = 0; i < 8; ++i) gsum += wred[i];   // waves 2..7 contributed 0
        gold_part[c] = gsum;
    }

    float etl[16];
#pragma unroll
    for (int j = 0; j < 16; ++j) etl[j] = __expf(trans[n * 32 + h * 16 + j]);

    float* vrow = &vb[wave][0];
    float v  = __expf(trans[n * 32 + p] + fl[n]);   // identical in both halves
    float sg = 0.f;
    for (int s = 1; s < L_CHUNK; ++s) {
        vrow[lane] = v;                             // vrow[k] = v[k] (dup at 32+k)
        __builtin_amdgcn_s_waitcnt(0xC07F);         // lgkmcnt(0): wave-coherent LDS
        float a0 = 0.f, a1 = 0.f, a2 = 0.f, a3 = 0.f;
#pragma unroll
        for (int q = 0; q < 4; ++q) {
            const float4 wv = *(const float4*)&vrow[h * 16 + q * 4];
            a0 = __builtin_fmaf(etl[q * 4 + 0], wv.x, a0);
            a1 = __builtin_fmaf(etl[q * 4 + 1], wv.y, a1);
            a2 = __builtin_fmaf(etl[q * 4 + 2], wv.z, a2);
            a3 = __builtin_fmaf(etl[q * 4 + 3], wv.w, a3);
        }
        float part = (a0 + a1) + (a2 + a3);
        part += __shfl_xor(part, 32);               // merge halves: full dot in all lanes
        v = __expf(fl[s * 32 + n]) * part;
        if ((s & 7) == 7) {
            float m = v;
#pragma unroll
            for (int off = 16; off; off >>= 1) m = fmaxf(m, __shfl_xor(m, off, 32));
            if (m > 0.f) { v *= 1.0f / m; sg += __logf(m); }
        }
    }
    if (h == 0) {
        QT[(c * 32 + p) * 32 + n] = v;
        if (n == 0) sigma[c * 32 + p] = sg;
    }
}

// ---------------- CRF pass B: parallel matrix fold ----------------
__global__ __launch_bounds__(1024) void crf_fold(const float* __restrict__ Qin,
                                                 const float* __restrict__ Sin,
                                                 const int fold, const int final,
                                                 float* __restrict__ Qout,
                                                 float* __restrict__ Sout,
                                                 const float* __restrict__ trans,
                                                 const float* __restrict__ gold_part,
                                                 const int* __restrict__ lab,
                                                 float* __restrict__ out) {
    __shared__ float A[32][33];
    __shared__ float M[32][33];
    __shared__ float sgf[32];
    __shared__ float gold_s;

    const int t = threadIdx.x;
    const int p = t >> 5, n = t & 31;
    const int c0 = blockIdx.x * fold;

    if (final && t == 0) {
        float s = 0.f;
#pragma unroll
        for (int i = 0; i < K_CHUNKS; ++i) s += gold_part[i];
        gold_s = s + trans[STOP_TAG * T_TAG + lab[S_LEN - 1]];
    }

    A[n][p] = Qin[(size_t)(c0 * 32 + p) * 32 + n];
    float sA = Sin[c0 * 32 + p];
    float mreg = Qin[(size_t)((c0 + 1) * 32 + p) * 32 + n];

    for (int i = 1; i < fold; ++i) {
        const float sMn = Sin[(c0 + i) * 32 + n];
        float mmax = sMn;
#pragma unroll
        for (int off = 16; off; off >>= 1) mmax = fmaxf(mmax, __shfl_xor(mmax, off, 32));
        const float sMp = Sin[(c0 + i) * 32 + p];
        __syncthreads();
        M[n][p] = mreg * __expf(sMp - mmax);
        if (i + 1 < fold) mreg = Qin[(size_t)((c0 + i + 1) * 32 + p) * 32 + n];
        __syncthreads();
        float acc = 0.f;
#pragma unroll 8
        for (int k = 0; k < 32; ++k)
            acc += M[n][k] * A[k][p];
        float cm = acc;
#pragma unroll
        for (int off = 16; off; off >>= 1) cm = fmaxf(cm, __shfl_xor(cm, off, 32));
        cm = fmaxf(cm, 1e-37f);
        __syncthreads();
        A[n][p] = acc / cm;
        sA = sA + mmax + __logf(cm);
    }
    __syncthreads();

    if (!final) {
        Qout[(size_t)(blockIdx.x * 32 + p) * 32 + n] = A[n][p];
        if (n == 0) Sout[blockIdx.x * 32 + p] = sA;
        return;
    }

    if (n == 0) sgf[p] = sA;
    __syncthreads();
    if (t < 32) {
        float v = A[t][START_TAG] * __expf(trans[STOP_TAG * T_TAG + t]);
#pragma unroll
        for (int off = 16; off; off >>= 1) v += __shfl_xor(v, off, 32);
        if (t == 0) out[0] = sgf[START_TAG] + __logf(v) - gold_s;
    }
}

// ---------------- launch ----------------
extern "C" void kernel_launch(void* const* d_in, const int* in_sizes, int n_in,
                              void* d_out, int out_size, void* d_ws, size_t ws_size,
                              hipStream_t stream) {
    const int*   ctx   = (const int*)d_in[0];
    const float* gz    = (const float*)d_in[1];
    const int*   lab   = (const int*)d_in[2];
    const float* emb   = (const float*)d_in[3];
    const float* w1    = (const float*)d_in[4];
    const float* b1    = (const float*)d_in[5];
    const float* w2    = (const float*)d_in[6];
    const float* b2    = (const float*)d_in[7];
    const float* trans = (const float*)d_in[8];
    float* out = (float*)d_out;

    char* ws = (char*)d_ws;
    bf16_t* W1b = (bf16_t*)(ws + 0);               // 1024*3456*2 =  7,077,888
    bf16_t* EB  = (bf16_t*)(ws + 7077888);         // 8000*128*2  =  2,048,000
    bf16_t* Xg  = (bf16_t*)(ws + 9126400);         // 8192*768*2  = 12,582,912
    float*  Fp  = (float*)(ws + 21709312);         // 8*8192*32*4 =  8,388,608
    float*  goldp = (float*)(ws + 30097920);       // 64*4        =        256
    float*  QT  = (float*)(ws + 31146496);         // 64*32*32*4  =    262,144
    float*  sg  = (float*)(ws + 31408640);         // 64*32*4     =      8,192
    float*  Q1  = (float*)(ws + 31416832);         // 8*32*32*4   =     32,768
    float*  S1  = (float*)(ws + 31449600);         // 8*32*4      =      1,024

    build_all<<<3572, 256, 0, stream>>>(ctx, gz, emb, w1, Xg, W1b, EB);
    gemm1<<<dim3(S_LEN / 128, H_DIM / 128), 512, 0, stream>>>(ctx, EB, Xg, W1b, b1, w2, b2, Fp);
    crfA<<<K_CHUNKS * 4, 512, 0, stream>>>(Fp, trans, QT, sg, lab, goldp);
    crf_fold<<<8, 1024, 0, stream>>>(QT, sg, 8, 0, Q1, S1, trans, nullptr, nullptr, nullptr);
    crf_fold<<<1, 1024, 0, stream>>>(Q1, S1, 8, 1, nullptr, nullptr, trans, goldp, lab, out);
}

// Round 14
// 220.245 us; speedup vs baseline: 1.0148x; 1.0148x over previous
//
#include <hip/hip_runtime.h>

#define S_LEN 8192
#define C_CTX 21
#define E_DIM 128
#define G_DIM 36
#define H_DIM 1024
#define T_TAG 32
#define D_RAW 3444          // 21*(128+36)
#define DP 3456             // emb-first K layout: 21*128=2688 emb | 756 gz | 12 pad
#define GZP 768             // padded gz width
#define START_TAG 30
#define STOP_TAG 31
#define NEGV -10000.0f
#define K_CHUNKS 64
#define L_CHUNK 128         // K_CHUNKS * L_CHUNK == S_LEN

typedef __bf16 bf16_t;
typedef __bf16 bf16x4 __attribute__((ext_vector_type(4)));
typedef __bf16 bf16x8 __attribute__((ext_vector_type(8)));
typedef float  f32x4  __attribute__((ext_vector_type(4)));

__device__ inline void async_copy16(const bf16_t* g, bf16_t* l) {
    __builtin_amdgcn_global_load_lds(
        (const __attribute__((address_space(1))) void*)g,
        (__attribute__((address_space(3))) void*)l, 16, 0, 0);
}

// ---------------- Phase 0: materialize W1b (emb-first K order), Xg, emb_bf --
// blocks 0..1023: W1b rows | 1024..3071: Xg (4 seq rows each) | 3072..3571: emb->bf16
__global__ void build_all(const int* __restrict__ ctx, const float* __restrict__ gz,
                          const float* __restrict__ emb, const float* __restrict__ w1,
                          bf16_t* __restrict__ Xg, bf16_t* __restrict__ W,
                          bf16_t* __restrict__ EB) {
    const int b = blockIdx.x;
    if (b < 1024) {                       // W1b row h, permuted K
        const int h = b;
        for (int g = threadIdx.x; g < DP / 4; g += 256) {
            bf16x4 o;
            if (g < 672) {                // emb region: knew = g*4; c=knew>>7, e=knew&127
                const int knew = g * 4;
                const float4 v = *(const float4*)&w1[(size_t)h * D_RAW + (knew >> 7) * 164 + (knew & 127)];
                o = bf16x4{(bf16_t)v.x, (bf16_t)v.y, (bf16_t)v.z, (bf16_t)v.w};
            } else {                      // gz region: m = g*4-2688 -> c=m/36, j=m%36
                const int m = g * 4 - 2688;
                float t[4];
#pragma unroll
                for (int u = 0; u < 4; ++u) {
                    const int mm = m + u;
                    t[u] = (mm < 756) ? w1[(size_t)h * D_RAW + (mm / 36) * 164 + 128 + (mm % 36)] : 0.f;
                }
                o = bf16x4{(bf16_t)t[0], (bf16_t)t[1], (bf16_t)t[2], (bf16_t)t[3]};
            }
            *(bf16x4*)&W[(size_t)h * DP + g * 4] = o;
        }
    } else if (b < 3072) {                // Xg: packed gz copy + pad (756 -> 768)
        const int s_base = (b - 1024) * 4;
        for (int g = threadIdx.x; g < 4 * 192; g += 256) {
            const int r = g / 192, gg = g - r * 192;
            const int s = s_base + r;
            bf16x4 o = bf16x4{(bf16_t)0.f, (bf16_t)0.f, (bf16_t)0.f, (bf16_t)0.f};
            if (gg < 189) {               // 189*4 = 756 exactly
                const float4 v = *(const float4*)&gz[(size_t)s * 756 + gg * 4];
                o = bf16x4{(bf16_t)v.x, (bf16_t)v.y, (bf16_t)v.z, (bf16_t)v.w};
            }
            *(bf16x4*)&Xg[(size_t)s * GZP + gg * 4] = o;
        }
    } else {                              // emb f32 -> bf16, flat 8000*128
        const size_t base = (size_t)(b - 3072) * 2048;
        for (int g = threadIdx.x; g < 512; g += 256) {
            const float4 v = *(const float4*)&emb[base + g * 4];
            bf16x4 o = bf16x4{(bf16_t)v.x, (bf16_t)v.y, (bf16_t)v.z, (bf16_t)v.w};
            *(bf16x4*)&EB[base + g * 4] = o;
        }
    }
}

// ---------------- Phase 1: h = relu(X @ W1^T + b1); Fp = h @ w2_slice^T ----
// 128x128 tile, BK=64, 256 threads (4 waves, 2x2, 64x64 per wave), 2 blocks/CU.
// Double-buffered, prefetch distance 1, ONE barrier per tile. Round-9 loop
// order (frag ds_reads FIRST, then stage issues, then MFMA): stages issue in
// the MFMA shadow. This is the measured-best gemm1 (62 µs, MfmaUtil 40);
// R13's 8-wave variant raised LDS frag-traffic 1.5x and netted 0.
// Verified kg^(row&7) swizzle; emb A-tiles gather direct from EB via ctx LDS
// cache; fused feats epilogue.
__global__ __launch_bounds__(256) void gemm1(const int* __restrict__ ctx,
                                             const bf16_t* __restrict__ EB,
                                             const bf16_t* __restrict__ Xg,
                                             const bf16_t* __restrict__ W,
                                             const float* __restrict__ b1,
                                             const float* __restrict__ w2,
                                             const float* __restrict__ b2,
                                             float* __restrict__ Fp) {
    __shared__ bf16_t As[2][128 * 64];        // 2 x 16 KB
    __shared__ bf16_t Bs[2][128 * 64];        // 2 x 16 KB
    __shared__ unsigned short ctxs[128 * 21]; // 5.375 KB (total 69.4 KB -> 2 blocks/CU)
    const int tid  = threadIdx.x;
    const int wave = tid >> 6, lane = tid & 63;
    const int s0 = blockIdx.x * 128, h0 = blockIdx.y * 128;
    const int wm = (wave >> 1) * 64;     // 2 wave-rows
    const int wn = (wave & 1) * 64;      // 2 wave-cols

    const int arow = tid >> 3;                         // 0..31
    const int akg  = (tid & 7) ^ (arow & 7);           // inverse-swizzled source k-group
    const bf16_t* gB = W + (size_t)(h0 + arow) * DP + akg * 8;

    const int lrow  = lane & 15;
    const int khalf = lane >> 4;         // 0..3
    const int lr7   = lrow & 7;

    // ctx table -> LDS (u16): rows s0..s0+127, flat copy
    for (int j = tid; j < 128 * C_CTX; j += 256)
        ctxs[j] = (unsigned short)ctx[s0 * C_CTX + j];
    asm volatile("s_waitcnt lgkmcnt(0)" ::: "memory");
    __builtin_amdgcn_s_barrier();

    // prologue: stage tile 0 (emb, c=0) into buf 0 — 8 loads
    {
        const int e0 = akg * 8;
#pragma unroll
        for (int i = 0; i < 4; ++i) {
            const int cv = ctxs[(i * 32 + arow) * 21];
            async_copy16(EB + (size_t)cv * 128 + e0, &As[0][(i * 256 + tid) * 8]);
        }
#pragma unroll
        for (int i = 0; i < 4; ++i)
            async_copy16(gB + (size_t)i * 32 * DP, &Bs[0][(i * 256 + tid) * 8]);
    }
    asm volatile("s_waitcnt vmcnt(0)" ::: "memory");
    __builtin_amdgcn_s_barrier();

    f32x4 acc[4][4] = {};
    const int NT = DP / 64;              // 54 (tiles 0..41 emb, 42..53 gz)
    for (int t = 0; t < NT; ++t) {
        const int cur = t & 1, nxt = cur ^ 1;
        const int tt = t + 1;
        const bool st = tt < NT;

        // all register fragments for this K-tile: 8 A + 8 B = 16 ds_read_b128
        bf16x8 a[2][2][2];     // [sp][ks][mt]
        bf16x8 b[2][2][2];     // [qn][ks][nt]
#pragma unroll
        for (int ks = 0; ks < 2; ++ks) {
            const int kgr = ((ks * 4 + khalf) ^ lr7) * 8;
#pragma unroll
            for (int sp = 0; sp < 2; ++sp)
#pragma unroll
                for (int mt = 0; mt < 2; ++mt)
                    a[sp][ks][mt] = *(const bf16x8*)&As[cur][(wm + sp * 32 + mt * 16 + lrow) * 64 + kgr];
#pragma unroll
            for (int qn = 0; qn < 2; ++qn)
#pragma unroll
                for (int nt = 0; nt < 2; ++nt)
                    b[qn][ks][nt] = *(const bf16x8*)&Bs[cur][(wn + qn * 32 + nt * 16 + lrow) * 64 + kgr];
        }
        // stage next tile into the other buffer (its readers finished at t-1)
        if (st) {
            if (tt < 42) {
                const int c_ = tt >> 1;
                const int e0 = (tt & 1) * 64 + akg * 8;
#pragma unroll
                for (int i = 0; i < 4; ++i) {
                    const int cv = ctxs[(i * 32 + arow) * 21 + c_];
                    async_copy16(EB + (size_t)cv * 128 + e0, &As[nxt][(i * 256 + tid) * 8]);
                }
            } else {
                const int m0 = (tt - 42) * 64 + akg * 8;
#pragma unroll
                for (int i = 0; i < 4; ++i)
                    async_copy16(Xg + (size_t)(s0 + i * 32 + arow) * GZP + m0, &As[nxt][(i * 256 + tid) * 8]);
            }
#pragma unroll
            for (int i = 0; i < 4; ++i)
                async_copy16(gB + (size_t)i * 32 * DP + tt * 64, &Bs[nxt][(i * 256 + tid) * 8]);
        }
        __builtin_amdgcn_s_setprio(1);
#pragma unroll
        for (int ks = 0; ks < 2; ++ks)
#pragma unroll
            for (int sp = 0; sp < 2; ++sp)
#pragma unroll
                for (int qn = 0; qn < 2; ++qn)
#pragma unroll
                    for (int mt = 0; mt < 2; ++mt)
#pragma unroll
                        for (int nt = 0; nt < 2; ++nt)
                            acc[sp * 2 + mt][qn * 2 + nt] = __builtin_amdgcn_mfma_f32_16x16x32_bf16(
                                a[sp][ks][mt], b[qn][ks][nt], acc[sp * 2 + mt][qn * 2 + nt], 0, 0, 0);
        __builtin_amdgcn_s_setprio(0);
        if (st) asm volatile("s_waitcnt vmcnt(0)" ::: "memory");
        __builtin_amdgcn_s_barrier();
    }

    // ---- fused feats epilogue ----
    bf16_t* Hl = &As[0][0];              // 128 x 128 bf16 (32 KB, spans As[0..1])
    bf16_t* Wl = &Bs[0][0];              // 32 x 128 bf16 (8 KB)

#pragma unroll
    for (int rep = 0; rep < 2; ++rep) {
        const int t8 = tid >> 3;            // 0..31 tag
        const int hl = (tid & 7) * 2 + rep; // 0..15 k-group
        const float* wsrc = w2 + (size_t)t8 * H_DIM + h0 + hl * 8;
        const float4 y0 = *(const float4*)wsrc;
        const float4 y1 = *(const float4*)(wsrc + 4);
        bf16x8 wv = {(bf16_t)y0.x, (bf16_t)y0.y, (bf16_t)y0.z, (bf16_t)y0.w,
                     (bf16_t)y1.x, (bf16_t)y1.y, (bf16_t)y1.z, (bf16_t)y1.w};
        *(bf16x8*)&Wl[(t8 * 16 + (hl ^ (t8 & 7))) * 8] = wv;
    }

    const int crow = (lane >> 4) * 4;
    const int ccol = lane & 15;
#pragma unroll
    for (int nt = 0; nt < 4; ++nt) {
        const int jl = wn + nt * 16 + ccol;          // 0..127 local h
        const float bv = b1[h0 + jl];
#pragma unroll
        for (int mt = 0; mt < 4; ++mt) {
#pragma unroll
            for (int r = 0; r < 4; ++r) {
                const int sl = wm + mt * 16 + crow + r;    // 0..127 local s
                const float v = acc[mt][nt][r] + bv;
                Hl[sl * 128 + ((jl >> 3) ^ (sl & 7)) * 8 + (jl & 7)] = (bf16_t)fmaxf(v, 0.f);
            }
        }
    }
    __syncthreads();

    f32x4 acc2[2][2] = {};
    const int wm2 = wave * 32;
#pragma unroll
    for (int ks = 0; ks < 4; ++ks) {
        const int slot = ((ks * 4 + khalf) ^ lr7) * 8;
        bf16x8 ah[2], bw[2];
#pragma unroll
        for (int mt = 0; mt < 2; ++mt)
            ah[mt] = *(const bf16x8*)&Hl[(wm2 + mt * 16 + lrow) * 128 + slot];
#pragma unroll
        for (int nt = 0; nt < 2; ++nt)
            bw[nt] = *(const bf16x8*)&Wl[(nt * 16 + lrow) * 128 + slot];
#pragma unroll
        for (int mt = 0; mt < 2; ++mt)
#pragma unroll
            for (int nt = 0; nt < 2; ++nt)
                acc2[mt][nt] = __builtin_amdgcn_mfma_f32_16x16x32_bf16(ah[mt], bw[nt], acc2[mt][nt], 0, 0, 0);
    }
    const int bj = h0 >> 7;
#pragma unroll
    for (int nt = 0; nt < 2; ++nt) {
        const int tcol = nt * 16 + ccol;
        const float badd = (bj == 7) ? b2[tcol] : 0.f;
#pragma unroll
        for (int mt = 0; mt < 2; ++mt) {
#pragma unroll
            for (int r = 0; r < 4; ++r) {
                const int sr = s0 + wm2 + mt * 16 + crow + r;
                Fp[((size_t)bj * S_LEN + sr) * T_TAG + tcol] = acc2[mt][nt][r] + badd;
            }
        }
    }
}

// ---------------- CRF pass A: per-chunk matrix-chain products + gold partial
// ONE chain per 64-lane wave; 2048 waves = 2 waves/SIMD. fl (the chunk's F
// rows, already in LDS for the chain) additionally feeds a per-chunk gold
// partial computed by the (blockIdx&3)==0 duplicate. Replaces the final
// fold's strided gold pass and the Fsum buffer entirely.
__global__ __launch_bounds__(512) void crfA(const float* __restrict__ Fp,
                                            const float* __restrict__ trans,
                                            float* __restrict__ QT,
                                            float* __restrict__ sigma,
                                            const int* __restrict__ lab,
                                            float* __restrict__ gold_part) {
    __shared__ float fl[L_CHUNK * 32];
    __shared__ float vb[8][64];
    __shared__ float wred[8];
    const int c    = blockIdx.x >> 2;
    const int tid  = threadIdx.x;
    const int wave = tid >> 6;
    const int lane = tid & 63;
    const int n    = lane & 31;
    const int h    = lane >> 5;                 // half: k in [h*16, h*16+16)
    const int p    = ((blockIdx.x & 3) << 3) + wave;
    const int s0   = c * L_CHUNK;
    for (int i = tid; i < L_CHUNK * 32; i += 512) {
        const size_t idx = (size_t)s0 * 32 + i;
        float accf = 0.f;
#pragma unroll
        for (int j = 0; j < 8; ++j) accf += Fp[(size_t)j * S_LEN * T_TAG + idx];
        fl[i] = accf;
    }
    __syncthreads();

    // gold partial (one duplicate block per chunk)
    const bool goldblk = (blockIdx.x & 3) == 0;
    float gterm = 0.f;
    if (goldblk && tid < L_CHUNK) {
        const int s  = s0 + tid;
        const int tg = lab[s];
        const int tp = (s == 0) ? START_TAG : lab[s - 1];
        gterm = fl[tid * 32 + tg] + trans[tg * T_TAG + tp];
    }
#pragma unroll
    for (int off = 32; off; off >>= 1) gterm += __shfl_down(gterm, off, 64);
    if (goldblk && lane == 0) wred[wave] = gterm;
    __syncthreads();
    if (goldblk && tid == 0) {
        float gsum = 0.f;
#pragma unroll
        for (int i = 0; i < 8; ++i) gsum += wred[i];   // waves 2..7 contributed 0
        gold_part[c] = gsum;
    }

    float etl[16];
#pragma unroll
    for (int j = 0; j < 16; ++j) etl[j] = __expf(trans[n * 32 + h * 16 + j]);

    float* vrow = &vb[wave][0];
    float v  = __expf(trans[n * 32 + p] + fl[n]);   // identical in both halves
    float sg = 0.f;
    for (int s = 1; s < L_CHUNK; ++s) {
        vrow[lane] = v;                             // vrow[k] = v[k] (dup at 32+k)
        __builtin_amdgcn_s_waitcnt(0xC07F);         // lgkmcnt(0): wave-coherent LDS
        float a0 = 0.f, a1 = 0.f, a2 = 0.f, a3 = 0.f;
#pragma unroll
        for (int q = 0; q < 4; ++q) {
            const float4 wv = *(const float4*)&vrow[h * 16 + q * 4];
            a0 = __builtin_fmaf(etl[q * 4 + 0], wv.x, a0);
            a1 = __builtin_fmaf(etl[q * 4 + 1], wv.y, a1);
            a2 = __builtin_fmaf(etl[q * 4 + 2], wv.z, a2);
            a3 = __builtin_fmaf(etl[q * 4 + 3], wv.w, a3);
        }
        float part = (a0 + a1) + (a2 + a3);
        part += __shfl_xor(part, 32);               // merge halves: full dot in all lanes
        v = __expf(fl[s * 32 + n]) * part;
        if ((s & 7) == 7) {
            float m = v;
#pragma unroll
            for (int off = 16; off; off >>= 1) m = fmaxf(m, __shfl_xor(m, off, 32));
            if (m > 0.f) { v *= 1.0f / m; sg += __logf(m); }
        }
    }
    if (h == 0) {
        QT[(c * 32 + p) * 32 + n] = v;
        if (n == 0) sigma[c * 32 + p] = sg;
    }
}

// ---------------- CRF pass B: parallel matrix fold ----------------
__global__ __launch_bounds__(1024) void crf_fold(const float* __restrict__ Qin,
                                                 const float* __restrict__ Sin,
                                                 const int fold, const int final,
                                                 float* __restrict__ Qout,
                                                 float* __restrict__ Sout,
                                                 const float* __restrict__ trans,
                                                 const float* __restrict__ gold_part,
                                                 const int* __restrict__ lab,
                                                 float* __restrict__ out) {
    __shared__ float A[32][33];
    __shared__ float M[32][33];
    __shared__ float sgf[32];
    __shared__ float gold_s;

    const int t = threadIdx.x;
    const int p = t >> 5, n = t & 31;
    const int c0 = blockIdx.x * fold;

    if (final && t == 0) {
        float s = 0.f;
#pragma unroll
        for (int i = 0; i < K_CHUNKS; ++i) s += gold_part[i];
        gold_s = s + trans[STOP_TAG * T_TAG + lab[S_LEN - 1]];
    }

    A[n][p] = Qin[(size_t)(c0 * 32 + p) * 32 + n];
    float sA = Sin[c0 * 32 + p];
    float mreg = Qin[(size_t)((c0 + 1) * 32 + p) * 32 + n];

    for (int i = 1; i < fold; ++i) {
        const float sMn = Sin[(c0 + i) * 32 + n];
        float mmax = sMn;
#pragma unroll
        for (int off = 16; off; off >>= 1) mmax = fmaxf(mmax, __shfl_xor(mmax, off, 32));
        const float sMp = Sin[(c0 + i) * 32 + p];
        __syncthreads();
        M[n][p] = mreg * __expf(sMp - mmax);
        if (i + 1 < fold) mreg = Qin[(size_t)((c0 + i + 1) * 32 + p) * 32 + n];
        __syncthreads();
        float acc = 0.f;
#pragma unroll 8
        for (int k = 0; k < 32; ++k)
            acc += M[n][k] * A[k][p];
        float cm = acc;
#pragma unroll
        for (int off = 16; off; off >>= 1) cm = fmaxf(cm, __shfl_xor(cm, off, 32));
        cm = fmaxf(cm, 1e-37f);
        __syncthreads();
        A[n][p] = acc / cm;
        sA = sA + mmax + __logf(cm);
    }
    __syncthreads();

    if (!final) {
        Qout[(size_t)(blockIdx.x * 32 + p) * 32 + n] = A[n][p];
        if (n == 0) Sout[blockIdx.x * 32 + p] = sA;
        return;
    }

    if (n == 0) sgf[p] = sA;
    __syncthreads();
    if (t < 32) {
        float v = A[t][START_TAG] * __expf(trans[STOP_TAG * T_TAG + t]);
#pragma unroll
        for (int off = 16; off; off >>= 1) v += __shfl_xor(v, off, 32);
        if (t == 0) out[0] = sgf[START_TAG] + __logf(v) - gold_s;
    }
}

// ---------------- launch ----------------
extern "C" void kernel_launch(void* const* d_in, const int* in_sizes, int n_in,
                              void* d_out, int out_size, void* d_ws, size_t ws_size,
                              hipStream_t stream) {
    const int*   ctx   = (const int*)d_in[0];
    const float* gz    = (const float*)d_in[1];
    const int*   lab   = (const int*)d_in[2];
    const float* emb   = (const float*)d_in[3];
    const float* w1    = (const float*)d_in[4];
    const float* b1    = (const float*)d_in[5];
    const float* w2    = (const float*)d_in[6];
    const float* b2    = (const float*)d_in[7];
    const float* trans = (const float*)d_in[8];
    float* out = (float*)d_out;

    char* ws = (char*)d_ws;
    bf16_t* W1b = (bf16_t*)(ws + 0);               // 1024*3456*2 =  7,077,888
    bf16_t* EB  = (bf16_t*)(ws + 7077888);         // 8000*128*2  =  2,048,000
    bf16_t* Xg  = (bf16_t*)(ws + 9126400);         // 8192*768*2  = 12,582,912
    float*  Fp  = (float*)(ws + 21709312);         // 8*8192*32*4 =  8,388,608
    float*  goldp = (float*)(ws + 30097920);       // 64*4        =        256
    float*  QT  = (float*)(ws + 31146496);         // 64*32*32*4  =    262,144
    float*  sg  = (float*)(ws + 31408640);         // 64*32*4     =      8,192
    float*  Q1  = (float*)(ws + 31416832);         // 8*32*32*4   =     32,768
    float*  S1  = (float*)(ws + 31449600);         // 8*32*4      =      1,024

    build_all<<<3572, 256, 0, stream>>>(ctx, gz, emb, w1, Xg, W1b, EB);
    gemm1<<<dim3(S_LEN / 128, H_DIM / 128), 256, 0, stream>>>(ctx, EB, Xg, W1b, b1, w2, b2, Fp);
    crfA<<<K_CHUNKS * 4, 512, 0, stream>>>(Fp, trans, QT, sg, lab, goldp);
    crf_fold<<<8, 1024, 0, stream>>>(QT, sg, 8, 0, Q1, S1, trans, nullptr, nullptr, nullptr);
    crf_fold<<<1, 1024, 0, stream>>>(Q1, S1, 8, 1, nullptr, nullptr, trans, goldp, lab, out);
}